// Round 6
// baseline (296.503 us; speedup 1.0000x reference)
//
#include <hip/hip_runtime.h>
#include <hip/hip_bf16.h>

// SparseLinear: out[b,s,o] = sum_i x[b,s,i]*W[o,i] + bias[o]
// M=8192, N=4096, K=4096. fp32 in/out; bf16 MFMA compute.
// Pass 1: convert x,W fp32->bf16 into d_ws.
// Pass 2: 256x256-tile, BK=64, 8-wave, 4-phase-per-K-tile GEMM
//         (T1 XCD swizzle + T2 LDS XOR-swizzle + T3/T4 counted vmcnt + T5 setprio).
// Round-5 single change vs round-4 anchor: MFMA shape 16x16x32 -> 32x32x16
// (ceiling 2075 -> 2382 TF; 32 instead of 64 MFMA per K-tile per wave).
// [Round-6 = identical resubmit; round-5 bench died to infra (UnresponsiveContainer).]

typedef __attribute__((ext_vector_type(8)))  short bf16x8;
typedef __attribute__((ext_vector_type(16))) float f32x16;
typedef __attribute__((ext_vector_type(4)))  float f32x4;
typedef unsigned short u16;

__device__ __forceinline__ u16 f2bf(float f) {
  unsigned int u = __float_as_uint(f);
  u += 0x7FFF + ((u >> 16) & 1);
  return (u16)(u >> 16);
}

__global__ __launch_bounds__(256) void convert_f32_bf16(
    const float* __restrict__ src, u16* __restrict__ dst, long long n) {
  long long stride = (long long)gridDim.x * blockDim.x * 4;
  for (long long e = ((long long)blockIdx.x * blockDim.x + threadIdx.x) * 4;
       e < n; e += stride) {
    float4 v = *reinterpret_cast<const float4*>(src + e);
    ushort4 o;
    o.x = f2bf(v.x); o.y = f2bf(v.y); o.z = f2bf(v.z); o.w = f2bf(v.w);
    *reinterpret_cast<ushort4*>(dst + e) = o;
  }
}

__device__ __forceinline__ void async16(const void* g, void* l) {
  __builtin_amdgcn_global_load_lds(
      (const __attribute__((address_space(1))) void*)g,
      (__attribute__((address_space(3))) void*)l, 16, 0, 0);
}

#define BAR()   asm volatile("s_barrier" ::: "memory")
#define LGKM0() asm volatile("s_waitcnt lgkmcnt(0)" ::: "memory")
#define VM(n)   asm volatile("s_waitcnt vmcnt(" #n ")" ::: "memory")
#define PRIO1() __builtin_amdgcn_s_setprio(1)
#define PRIO0() __builtin_amdgcn_s_setprio(0)

// ---------------- 256x256 kernel, 32x32x16 MFMA ----------------
// Per-wave output: 128x64 = 4 m-frags(32 rows) x 2 n-frags(32 cols); K-tile 64
// = 4 k-steps of 16. LDS map (bytes): A: buf c -> c*32768, half h -> +h*16384
// (128 storage rows x 128B). B: +65536, same. Total 131072.
// A half h holds m-frags {2h,2h+1}: storage row sr = wm*64 + mfl*32 + (row&31).
// B half h holds n-frag h:          storage row sr = wn*32 + (col&31).
// Swizzle (involution): colbyte ^= ((sr&7)<<4)  [all frag strides are 8-row mult].

__global__ __launch_bounds__(512, 2) void gemm256_8ph(
    const u16* __restrict__ A, const u16* __restrict__ B,
    const float* __restrict__ bias, float* __restrict__ C,
    int M, int N, int K) {
  extern __shared__ char smem[];
  char* ldsA = smem;
  char* ldsB = smem + 65536;

  const int tid  = threadIdx.x;
  const int lane = tid & 63;
  const int wave = tid >> 6;
  const int wm = wave >> 2;  // 0..1
  const int wn = wave & 3;   // 0..3

  // T1: XCD-aware block swizzle (grid divisible by 8)
  const int nwg = gridDim.x;
  const int cpx = nwg >> 3;
  const int bid = blockIdx.x;
  const int swz = (bid & 7) * cpx + (bid >> 3);
  const int nbn = N >> 8;
  const int m0 = (swz / nbn) << 8;
  const int n0 = (swz % nbn) << 8;

  // staging: linear LDS dest (tid*16 within half), pre-swizzled global source
  const int d0 = tid * 16;
  const int sr0 = d0 >> 7;              // 0..63 (issue j=0); j=1 adds 64 to sr
  const int cb0 = (d0 & 127) ^ ((sr0 & 7) << 4);
  const int rA0 = ((sr0 >> 6) << 7) + (((sr0 >> 5) & 1) << 5) + (sr0 & 31);
  const int rB0 = ((sr0 >> 5) << 6) + (sr0 & 31);
  const u16* gA00 = A + (long long)(m0 + rA0) * K + (cb0 >> 1);
  const u16* gB00 = B + (long long)(n0 + rB0) * K + (cb0 >> 1);
  // sr+64 (issue j=1) adds exactly 128 logical rows for both A and B.

#define STAGE_A(c, h, S) do { \
  async16(gA00 + (long long)((h)*64)       * K + (S)*64, \
          ldsA + (c)*32768 + (h)*16384 + tid*16); \
  async16(gA00 + (long long)((h)*64 + 128) * K + (S)*64, \
          ldsA + (c)*32768 + (h)*16384 + 8192 + tid*16); \
} while (0)
#define STAGE_B(c, h, S) do { \
  async16(gB00 + (long long)((h)*32)       * K + (S)*64, \
          ldsB + (c)*32768 + (h)*16384 + tid*16); \
  async16(gB00 + (long long)((h)*32 + 128) * K + (S)*64, \
          ldsB + (c)*32768 + (h)*16384 + 8192 + tid*16); \
} while (0)

  // fragment read addressing (swizzled):
  // A row sr = wm*64 + mfl*32 + (lane&31); B row sr = wn*32 + (lane&31)
  // logical colbyte for k-step s: s*32 + ((lane>>5)<<4), XOR ((lane&7)<<4)
  const int l31  = lane & 31;
  const int kofs = (lane >> 5) << 4;
  const int xsw  = (lane & 7) << 4;
  const int csw[4] = { (0 * 32 + kofs) ^ xsw, (1 * 32 + kofs) ^ xsw,
                       (2 * 32 + kofs) ^ xsw, (3 * 32 + kofs) ^ xsw };
  const int arow = (wm * 64 + l31) * 128;
  const int brow = (wn * 32 + l31) * 128;

#define LDA(dst, c, h) do { \
  _Pragma("unroll") for (int mfl_ = 0; mfl_ < 2; ++mfl_) \
  _Pragma("unroll") for (int s_ = 0; s_ < 4; ++s_) \
    dst[mfl_][s_] = *(const bf16x8*)(ldsA + (c)*32768 + (h)*16384 + arow + mfl_*4096 + csw[s_]); \
} while (0)
#define LDB(dst, c, h) do { \
  _Pragma("unroll") for (int s_ = 0; s_ < 4; ++s_) \
    dst[s_] = *(const bf16x8*)(ldsB + (c)*32768 + (h)*16384 + brow + csw[s_]); \
} while (0)

  f32x16 acc[4][2] = {};

#define MM(ma, nb, af, bf) do { \
  _Pragma("unroll") for (int i_ = 0; i_ < 2; ++i_) \
  _Pragma("unroll") for (int s_ = 0; s_ < 4; ++s_) \
    acc[(ma)+i_][(nb)] = __builtin_amdgcn_mfma_f32_32x32x16_bf16( \
        af[i_][s_], bf[s_], acc[(ma)+i_][(nb)], 0, 0, 0); \
} while (0)

// One K-tile = 4 phases, 8 MFMA each (quadrant = 2 m-frags x 1 n-frag x K=64).
// Stage slots: a slot is overwritten only after the phase where its last
// ds_read drained + barrier. VM(8): in-flight = tile T+1 (8) + T+2 (8);
// drain to 8 => T+1 fully landed before next group reads it.
#define GROUP(c, S, DO_STAGE, WAITN) do { \
  bf16x8 a[2][4], a2[2][4], b[4], b2[4]; \
  LDA(a, c, 0); LDB(b, c, 0); \
  BAR(); LGKM0(); PRIO1(); MM(0, 0, a, b);   PRIO0(); BAR(); \
  LDA(a2, c, 1); \
  if (DO_STAGE) { STAGE_A(c, 0, S); STAGE_B(c, 0, S); } \
  BAR(); LGKM0(); PRIO1(); MM(2, 0, a2, b);  PRIO0(); BAR(); \
  LDB(b2, c, 1); \
  if (DO_STAGE) { STAGE_A(c, 1, S); } \
  BAR(); LGKM0(); PRIO1(); MM(2, 1, a2, b2); PRIO0(); BAR(); \
  if (DO_STAGE) { STAGE_B(c, 1, S); } \
  WAITN; \
  BAR();          PRIO1(); MM(0, 1, a, b2);  PRIO0(); BAR(); \
} while (0)

  // Prologue: stage tiles 0 and 1; wait for tile 0 (8 newest may fly).
  STAGE_A(0, 0, 0); STAGE_A(0, 1, 0); STAGE_B(0, 0, 0); STAGE_B(0, 1, 0);
  STAGE_A(1, 0, 1); STAGE_A(1, 1, 1); STAGE_B(1, 0, 1); STAGE_B(1, 1, 1);
  VM(8);
  __syncthreads();

  const int NT = K >> 6;
  for (int T = 0; T < NT - 2; ++T) {
    GROUP(T & 1, T + 2, 1, VM(8));
  }
  GROUP((NT - 2) & 1, 0, 0, VM(0));
  GROUP((NT - 1) & 1, 0, 0, (void)0);

  // Epilogue: 32x32 D layout col=lane&31, row=(reg&3)+8*(reg>>2)+4*(lane>>5)
  // [m74/m101-verified]; fuse bias.
  const int rbase = (lane >> 5) << 2;
#pragma unroll
  for (int mf = 0; mf < 4; ++mf) {
#pragma unroll
    for (int nf = 0; nf < 2; ++nf) {
      const int gn = n0 + wn * 64 + nf * 32 + l31;
      const float bv = bias[gn];
      float* cp = C + (long long)(m0 + wm * 128 + mf * 32 + rbase) * N + gn;
#pragma unroll
      for (int reg = 0; reg < 16; ++reg) {
        const int rofs = (reg & 3) + 8 * (reg >> 2);
        cp[(long long)rofs * N] = acc[mf][nf][reg] + bv;
      }
    }
  }
}

// ---------------- fallback: 128x128 kernel (static 16KB LDS) ----------------
__global__ __launch_bounds__(256) void gemm_bf16_bt(
    const u16* __restrict__ A, const u16* __restrict__ B,
    const float* __restrict__ bias, float* __restrict__ C,
    int M, int N, int K) {
  __shared__ u16 As[128 * 32];
  __shared__ u16 Bs[128 * 32];
  const int tid = threadIdx.x, lane = tid & 63, wave = tid >> 6;
  const int wr = wave >> 1, wc = wave & 1;
  const int nbn = N / 128;
  const int m0 = (blockIdx.x / nbn) * 128, n0 = (blockIdx.x % nbn) * 128;
  const int sr = tid >> 2, sc = (tid & 3) * 8;
  const u16* Ap0 = A + (long long)(m0 + sr) * K + sc;
  const u16* Ap1 = A + (long long)(m0 + 64 + sr) * K + sc;
  const u16* Bp0 = B + (long long)(n0 + sr) * K + sc;
  const u16* Bp1 = B + (long long)(n0 + 64 + sr) * K + sc;
  const int frow = lane & 15, fk = (lane >> 4) * 8;
  f32x4 acc[4][4] = {};
  for (int k0 = 0; k0 < K; k0 += 32) {
    async16(Ap0 + k0, As + tid * 8); async16(Ap1 + k0, As + 2048 + tid * 8);
    async16(Bp0 + k0, Bs + tid * 8); async16(Bp1 + k0, Bs + 2048 + tid * 8);
    __syncthreads();
    bf16x8 af[4], bfr[4];
#pragma unroll
    for (int i = 0; i < 4; ++i) {
      af[i]  = *reinterpret_cast<const bf16x8*>(As + (wr * 64 + i * 16 + frow) * 32 + fk);
      bfr[i] = *reinterpret_cast<const bf16x8*>(Bs + (wc * 64 + i * 16 + frow) * 32 + fk);
    }
#pragma unroll
    for (int i = 0; i < 4; ++i)
#pragma unroll
      for (int j = 0; j < 4; ++j)
        acc[i][j] = __builtin_amdgcn_mfma_f32_16x16x32_bf16(af[i], bfr[j], acc[i][j], 0, 0, 0);
    __syncthreads();
  }
  const int col0 = lane & 15, row4 = (lane >> 4) * 4;
#pragma unroll
  for (int i = 0; i < 4; ++i)
#pragma unroll
    for (int j = 0; j < 4; ++j) {
      const int n = n0 + wc * 64 + j * 16 + col0;
      const float bv = bias[n];
      const int mb = m0 + wr * 64 + i * 16 + row4;
#pragma unroll
      for (int r = 0; r < 4; ++r)
        C[(long long)(mb + r) * N + n] = acc[i][j][r] + bv;
    }
}

__global__ __launch_bounds__(256) void naive_gemm_f32(
    const float* __restrict__ x, const float* __restrict__ w,
    const float* __restrict__ bias, float* __restrict__ out,
    int M, int N, int K) {
  long long idx = (long long)blockIdx.x * 256 + threadIdx.x;
  if (idx >= (long long)M * N) return;
  int m = (int)(idx / N), n = (int)(idx % N);
  const float4* xr = reinterpret_cast<const float4*>(x + (long long)m * K);
  const float4* wr = reinterpret_cast<const float4*>(w + (long long)n * K);
  float s = 0.f;
  for (int k = 0; k < K / 4; ++k) {
    float4 a = xr[k], b = wr[k];
    s += a.x * b.x + a.y * b.y + a.z * b.z + a.w * b.w;
  }
  out[idx] = s + bias[n];
}

extern "C" void kernel_launch(void* const* d_in, const int* in_sizes, int n_in,
                              void* d_out, int out_size, void* d_ws,
                              size_t ws_size, hipStream_t stream) {
  const float* x    = (const float*)d_in[0];
  const float* w    = (const float*)d_in[1];
  const float* bias = (const float*)d_in[2];
  float* out = (float*)d_out;

  const int K = 4096, N = 4096;
  const long long xN = in_sizes[0];
  const long long wN = in_sizes[1];
  const int M = (int)(xN / K);

  const size_t need = (size_t)(xN + wN) * sizeof(u16);
  if (ws_size >= need) {
    u16* xb = (u16*)d_ws;
    u16* wb = xb + xN;
    convert_f32_bf16<<<2048, 256, 0, stream>>>(x, xb, xN);
    convert_f32_bf16<<<2048, 256, 0, stream>>>(w, wb, wN);
    hipError_t e = hipFuncSetAttribute(
        (const void*)gemm256_8ph,
        hipFuncAttributeMaxDynamicSharedMemorySize, 131072);
    if (e == hipSuccess && (M % 256) == 0 && (N % 256) == 0 && (K % 128) == 0) {
      const int grid = (M / 256) * (N / 256);  // 512
      gemm256_8ph<<<grid, 512, 131072, stream>>>(xb, wb, bias, out, M, N, K);
    } else {
      const int grid = (M / 128) * (N / 128);
      gemm_bf16_bt<<<grid, 256, 0, stream>>>(xb, wb, bias, out, M, N, K);
    }
  } else {
    const long long total = (long long)M * N;
    naive_gemm_f32<<<(unsigned)((total + 255) / 256), 256, 0, stream>>>(
        x, w, bias, out, M, N, K);
  }
}

// Round 7
// 268.410 us; speedup vs baseline: 1.1047x; 1.1047x over previous
//
#include <hip/hip_runtime.h>
#include <hip/hip_bf16.h>

// SparseLinear: out[b,s,o] = sum_i x[b,s,i]*W[o,i] + bias[o]
// M=8192, N=4096, K=4096. fp32 in/out; bf16 MFMA compute.
// Pass 1: convert x,W fp32->bf16 into d_ws.
// Pass 2: 256x256-tile, BK=64, 8-wave, 4-phase GEMM (16x16x32 MFMA).
// Round-7 vs round-4 anchor: ds_read register loads software-pipelined one
// phase ahead with COUNTED lgkmcnt (8/4/0/-), quadrant order (a,b)(a2,b)
// (a,b2)(a2,b2); next-tile a,b pre-issued in P4 after VM+BAR.
// (Round-6's 32x32x16 shape REVERTED: it introduced 2.5e7 bank conflicts.)

typedef __attribute__((ext_vector_type(8))) short bf16x8;
typedef __attribute__((ext_vector_type(4))) float f32x4;
typedef unsigned short u16;

__device__ __forceinline__ u16 f2bf(float f) {
  unsigned int u = __float_as_uint(f);
  u += 0x7FFF + ((u >> 16) & 1);
  return (u16)(u >> 16);
}

__global__ __launch_bounds__(256) void convert_f32_bf16(
    const float* __restrict__ src, u16* __restrict__ dst, long long n) {
  long long stride = (long long)gridDim.x * blockDim.x * 4;
  for (long long e = ((long long)blockIdx.x * blockDim.x + threadIdx.x) * 4;
       e < n; e += stride) {
    float4 v = *reinterpret_cast<const float4*>(src + e);
    ushort4 o;
    o.x = f2bf(v.x); o.y = f2bf(v.y); o.z = f2bf(v.z); o.w = f2bf(v.w);
    *reinterpret_cast<ushort4*>(dst + e) = o;
  }
}

__device__ __forceinline__ void async16(const void* g, void* l) {
  __builtin_amdgcn_global_load_lds(
      (const __attribute__((address_space(1))) void*)g,
      (__attribute__((address_space(3))) void*)l, 16, 0, 0);
}

#define BAR()   asm volatile("s_barrier" ::: "memory")
#define LGKM(n) asm volatile("s_waitcnt lgkmcnt(" #n ")" ::: "memory")
#define VM(n)   asm volatile("s_waitcnt vmcnt(" #n ")" ::: "memory")
#define PRIO1() __builtin_amdgcn_s_setprio(1)
#define PRIO0() __builtin_amdgcn_s_setprio(0)

// ---------------- 256x256 4-phase kernel, 16x16x32 MFMA ----------------
// LDS map (bytes): A: buf c -> c*32768, half h -> +h*16384 (128 rows x 128B).
//                  B: +65536, same. Total 131072.
// A half h holds m-frags {4h..4h+3}: storage row sr = wm*64 + mfl*16 + (r&15).
// B half h holds n-frags {2h,2h+1}:  storage row sr = wn*32 + nfl*16 + (r&15).
// Swizzle (involution): colbyte ^= ((sr&7)<<4).

__global__ __launch_bounds__(512, 2) void gemm256_8ph(
    const u16* __restrict__ A, const u16* __restrict__ B,
    const float* __restrict__ bias, float* __restrict__ C,
    int M, int N, int K) {
  extern __shared__ char smem[];
  char* ldsA = smem;
  char* ldsB = smem + 65536;

  const int tid  = threadIdx.x;
  const int lane = tid & 63;
  const int wave = tid >> 6;
  const int wm = wave >> 2;  // 0..1
  const int wn = wave & 3;   // 0..3

  // T1: XCD-aware block swizzle (grid divisible by 8)
  const int nwg = gridDim.x;
  const int cpx = nwg >> 3;
  const int bid = blockIdx.x;
  const int swz = (bid & 7) * cpx + (bid >> 3);
  const int nbn = N >> 8;
  const int m0 = (swz / nbn) << 8;
  const int n0 = (swz % nbn) << 8;

  // staging: linear LDS dest (tid*16 within half), pre-swizzled global source
  const int d0 = tid * 16;
  const int sr0 = d0 >> 7;              // 0..63 (issue j=0); j=1 adds 64 to sr
  const int cb0 = (d0 & 127) ^ ((sr0 & 7) << 4);
  const int rA0 = ((sr0 >> 6) << 7) + (((sr0 >> 4) & 3) << 4) + (sr0 & 15);
  const int rB0 = ((sr0 >> 5) << 6) + (((sr0 >> 4) & 1) << 4) + (sr0 & 15);
  const u16* gA00 = A + (long long)(m0 + rA0) * K + (cb0 >> 1);
  const u16* gB00 = B + (long long)(n0 + rB0) * K + (cb0 >> 1);

#define STAGE_A(c, h, S) do { \
  async16(gA00 + (long long)((h)*64)       * K + (S)*64, \
          ldsA + (c)*32768 + (h)*16384 + tid*16); \
  async16(gA00 + (long long)((h)*64 + 128) * K + (S)*64, \
          ldsA + (c)*32768 + (h)*16384 + 8192 + tid*16); \
} while (0)
#define STAGE_B(c, h, S) do { \
  async16(gB00 + (long long)((h)*32)       * K + (S)*64, \
          ldsB + (c)*32768 + (h)*16384 + tid*16); \
  async16(gB00 + (long long)((h)*32 + 128) * K + (S)*64, \
          ldsB + (c)*32768 + (h)*16384 + 8192 + tid*16); \
} while (0)

  // fragment read addresses (swizzled)
  const int l15 = lane & 15;
  const int csw0 = (((lane >> 4) * 16))      ^ ((lane & 7) << 4);  // kk=0
  const int csw1 = (64 + ((lane >> 4) * 16)) ^ ((lane & 7) << 4);  // kk=1
  const int arow = (wm * 64 + l15) * 128;
  const int brow = (wn * 32 + l15) * 128;

#define LDA(dst, c, h) do { \
  _Pragma("unroll") for (int mfl_ = 0; mfl_ < 4; ++mfl_) { \
    dst[mfl_][0] = *(const bf16x8*)(ldsA + (c)*32768 + (h)*16384 + arow + mfl_*2048 + csw0); \
    dst[mfl_][1] = *(const bf16x8*)(ldsA + (c)*32768 + (h)*16384 + arow + mfl_*2048 + csw1); \
  } } while (0)
#define LDB(dst, c, h) do { \
  _Pragma("unroll") for (int nfl_ = 0; nfl_ < 2; ++nfl_) { \
    dst[nfl_][0] = *(const bf16x8*)(ldsB + (c)*32768 + (h)*16384 + brow + nfl_*2048 + csw0); \
    dst[nfl_][1] = *(const bf16x8*)(ldsB + (c)*32768 + (h)*16384 + brow + nfl_*2048 + csw1); \
  } } while (0)

  f32x4 acc[8][4] = {};

#define MM(mb, nb, af, bf) do { \
  _Pragma("unroll") for (int i_ = 0; i_ < 4; ++i_) \
  _Pragma("unroll") for (int j_ = 0; j_ < 2; ++j_) \
  _Pragma("unroll") for (int kk_ = 0; kk_ < 2; ++kk_) \
    acc[(mb)+i_][(nb)+j_] = __builtin_amdgcn_mfma_f32_16x16x32_bf16( \
        af[i_][kk_], bf[j_][kk_], acc[(mb)+i_][(nb)+j_], 0, 0, 0); \
} while (0)

// One K-tile = 4 phases, 16 MFMA each. Register loads pipelined one phase
// ahead; counted lgkmcnt (FIFO DS completion): P1 waits first-12 (a,b, issued
// prev P4), P2 waits a2 (issued P1), P3 waits b2 (issued P2), P4 waits none.
// Stage slots: half last-read drains before that phase's trailing BAR =>
// overwrite is legal one phase later. VM(8): tiles T+1(8)+T+2(8) in flight,
// drain to 8 => T+1 fully landed; next-tile a,b reads issued AFTER VM+BAR.
#define GROUP(c, S, DO_STAGE, WAITN, DO_NEXT) do { \
  LDA(a2, c, 1); \
  BAR(); LGKM(8); PRIO1(); MM(0, 0, a, b);   PRIO0(); BAR(); \
  LDB(b2, c, 1); \
  if (DO_STAGE) { STAGE_A(c, 0, S); STAGE_B(c, 0, S); } \
  BAR(); LGKM(4); PRIO1(); MM(4, 0, a2, b);  PRIO0(); BAR(); \
  if (DO_STAGE) { STAGE_A(c, 1, S); } \
  BAR(); LGKM(0); PRIO1(); MM(0, 2, a, b2);  PRIO0(); BAR(); \
  if (DO_STAGE) { STAGE_B(c, 1, S); } \
  WAITN; \
  BAR(); \
  if (DO_NEXT) { LDA(a, (c) ^ 1, 0); LDB(b, (c) ^ 1, 0); } \
  PRIO1(); MM(4, 2, a2, b2); PRIO0(); BAR(); \
} while (0)

  // Prologue: stage tiles 0 and 1; wait for tile 0 (8 newest may fly).
  STAGE_A(0, 0, 0); STAGE_A(0, 1, 0); STAGE_B(0, 0, 0); STAGE_B(0, 1, 0);
  STAGE_A(1, 0, 1); STAGE_A(1, 1, 1); STAGE_B(1, 0, 1); STAGE_B(1, 1, 1);
  VM(8);
  __syncthreads();

  bf16x8 a[4][2], a2[4][2], b[2][2], b2[2][2];
  LDA(a, 0, 0); LDB(b, 0, 0);

  const int NT = K >> 6;
  for (int T = 0; T < NT - 2; ++T) {
    GROUP(T & 1, T + 2, 1, VM(8), 1);
  }
  GROUP((NT - 2) & 1, 0, 0, VM(0), 1);
  GROUP((NT - 1) & 1, 0, 0, (void)0, 0);

  // Epilogue: D layout col=lane&15, row=(lane>>4)*4+reg; fuse bias.
  const int row4 = (lane >> 4) << 2;
#pragma unroll
  for (int mf = 0; mf < 8; ++mf) {
#pragma unroll
    for (int nf = 0; nf < 4; ++nf) {
      const int gn = n0 + wn * 64 + nf * 16 + l15;
      const float bv = bias[gn];
      float* cp = C + (long long)(m0 + wm * 128 + mf * 16 + row4) * N + gn;
#pragma unroll
      for (int r = 0; r < 4; ++r) cp[(long long)r * N] = acc[mf][nf][r] + bv;
    }
  }
}

// ---------------- fallback: 128x128 kernel (static 16KB LDS) ----------------
__global__ __launch_bounds__(256) void gemm_bf16_bt(
    const u16* __restrict__ A, const u16* __restrict__ B,
    const float* __restrict__ bias, float* __restrict__ C,
    int M, int N, int K) {
  __shared__ u16 As[128 * 32];
  __shared__ u16 Bs[128 * 32];
  const int tid = threadIdx.x, lane = tid & 63, wave = tid >> 6;
  const int wr = wave >> 1, wc = wave & 1;
  const int nbn = N / 128;
  const int m0 = (blockIdx.x / nbn) * 128, n0 = (blockIdx.x % nbn) * 128;
  const int sr = tid >> 2, sc = (tid & 3) * 8;
  const u16* Ap0 = A + (long long)(m0 + sr) * K + sc;
  const u16* Ap1 = A + (long long)(m0 + 64 + sr) * K + sc;
  const u16* Bp0 = B + (long long)(n0 + sr) * K + sc;
  const u16* Bp1 = B + (long long)(n0 + 64 + sr) * K + sc;
  const int frow = lane & 15, fk = (lane >> 4) * 8;
  f32x4 acc[4][4] = {};
  for (int k0 = 0; k0 < K; k0 += 32) {
    async16(Ap0 + k0, As + tid * 8); async16(Ap1 + k0, As + 2048 + tid * 8);
    async16(Bp0 + k0, Bs + tid * 8); async16(Bp1 + k0, Bs + 2048 + tid * 8);
    __syncthreads();
    bf16x8 af[4], bfr[4];
#pragma unroll
    for (int i = 0; i < 4; ++i) {
      af[i]  = *reinterpret_cast<const bf16x8*>(As + (wr * 64 + i * 16 + frow) * 32 + fk);
      bfr[i] = *reinterpret_cast<const bf16x8*>(Bs + (wc * 64 + i * 16 + frow) * 32 + fk);
    }
#pragma unroll
    for (int i = 0; i < 4; ++i)
#pragma unroll
      for (int j = 0; j < 4; ++j)
        acc[i][j] = __builtin_amdgcn_mfma_f32_16x16x32_bf16(af[i], bfr[j], acc[i][j], 0, 0, 0);
    __syncthreads();
  }
  const int col0 = lane & 15, row4 = (lane >> 4) * 4;
#pragma unroll
  for (int i = 0; i < 4; ++i)
#pragma unroll
    for (int j = 0; j < 4; ++j) {
      const int n = n0 + wc * 64 + j * 16 + col0;
      const float bv = bias[n];
      const int mb = m0 + wr * 64 + i * 16 + row4;
#pragma unroll
      for (int r = 0; r < 4; ++r)
        C[(long long)(mb + r) * N + n] = acc[i][j][r] + bv;
    }
}

__global__ __launch_bounds__(256) void naive_gemm_f32(
    const float* __restrict__ x, const float* __restrict__ w,
    const float* __restrict__ bias, float* __restrict__ out,
    int M, int N, int K) {
  long long idx = (long long)blockIdx.x * 256 + threadIdx.x;
  if (idx >= (long long)M * N) return;
  int m = (int)(idx / N), n = (int)(idx % N);
  const float4* xr = reinterpret_cast<const float4*>(x + (long long)m * K);
  const float4* wr = reinterpret_cast<const float4*>(w + (long long)n * K);
  float s = 0.f;
  for (int k = 0; k < K / 4; ++k) {
    float4 a = xr[k], b = wr[k];
    s += a.x * b.x + a.y * b.y + a.z * b.z + a.w * b.w;
  }
  out[idx] = s + bias[n];
}

extern "C" void kernel_launch(void* const* d_in, const int* in_sizes, int n_in,
                              void* d_out, int out_size, void* d_ws,
                              size_t ws_size, hipStream_t stream) {
  const float* x    = (const float*)d_in[0];
  const float* w    = (const float*)d_in[1];
  const float* bias = (const float*)d_in[2];
  float* out = (float*)d_out;

  const int K = 4096, N = 4096;
  const long long xN = in_sizes[0];
  const long long wN = in_sizes[1];
  const int M = (int)(xN / K);

  const size_t need = (size_t)(xN + wN) * sizeof(u16);
  if (ws_size >= need) {
    u16* xb = (u16*)d_ws;
    u16* wb = xb + xN;
    convert_f32_bf16<<<2048, 256, 0, stream>>>(x, xb, xN);
    convert_f32_bf16<<<2048, 256, 0, stream>>>(w, wb, wN);
    hipError_t e = hipFuncSetAttribute(
        (const void*)gemm256_8ph,
        hipFuncAttributeMaxDynamicSharedMemorySize, 131072);
    if (e == hipSuccess && (M % 256) == 0 && (N % 256) == 0 && (K % 128) == 0) {
      const int grid = (M / 256) * (N / 256);  // 512
      gemm256_8ph<<<grid, 512, 131072, stream>>>(xb, wb, bias, out, M, N, K);
    } else {
      const int grid = (M / 128) * (N / 128);
      gemm_bf16_bt<<<grid, 256, 0, stream>>>(xb, wb, bias, out, M, N, K);
    }
  } else {
    const long long total = (long long)M * N;
    naive_gemm_f32<<<(unsigned)((total + 255) / 256), 256, 0, stream>>>(
        x, w, bias, out, M, N, K);
  }
}